// Round 1
// 401.076 us; speedup vs baseline: 1.0668x; 1.0668x over previous
//
#include <hip/hip_runtime.h>

// Fuzzy c-means on MI355X. N=300000, D=64, c=64, m=2 (p=2), 25 updates + init.
// R4: MFMA rewrite (432us). R5: bf16 xbf copy, nb=512 (427us).
// R6: pass is VALU-issue-bound (12.2us busy/pass) + 5.25M LDS conflict cycles.
//  - um pack: v_cvt_pk_bf16_f32 (2 instr/pt) replaces 22-op manual RNE pack.
//  - pad mask folded into rrs (per-point) instead of per-element cmp+cndmask.
//  - den computed by MFMA vs ones-fragment (matrix pipe is ~idle) -> den and
//    num now both use bf16 um (rounding cancels in num/den).
//  - staging decomposition p=i&63 kills the 16-way transpose-scatter bank
//    conflicts (writes become lane-consecutive shorts); addresses hoisted.

#define DM 64
#define CL 64
#define PARTIAL_STRIDE 4160      // 64*64 num + 64 den
#define MAX_ITER 25
#define MAX_BLOCKS 512
#define LDP 72                   // padded row length (bf16) for Xb/XTb/umT

typedef __attribute__((ext_vector_type(8))) short bf16x8;   // MFMA A/B frag (4 VGPRs)
typedef __attribute__((ext_vector_type(4))) float f32x4;    // MFMA C/D frag

__device__ __forceinline__ unsigned f2bf1(float f) {        // fp32 -> bf16 (RNE)
  unsigned u = __builtin_bit_cast(unsigned, f);
  return (u + 0x7FFFu + ((u >> 16) & 1u)) >> 16;
}
__device__ __forceinline__ unsigned pkbf(float a, float b) {
  return f2bf1(a) | (f2bf1(b) << 16);
}
// HW packed fp32->2xbf16 (RNE), gfx950. %1 -> low half, %2 -> high half.
__device__ __forceinline__ unsigned cvtpk_bf16(float a, float b) {
  unsigned r;
  asm("v_cvt_pk_bf16_f32 %0, %1, %2" : "=v"(r) : "v"(a), "v"(b));
  return r;
}

// 64-lane sum (reduce kernel only): DPP row reduce + bcast, result via lane 63.
__device__ __forceinline__ float wave_sum(float v) {
#define DPPADD(ctrl, rmask)                                                  \
  v += __builtin_bit_cast(float, __builtin_amdgcn_update_dpp(                \
           0, __builtin_bit_cast(int, v), ctrl, rmask, 0xf, false));
  DPPADD(0x111, 0xf)   // row_shr:1
  DPPADD(0x112, 0xf)   // row_shr:2
  DPPADD(0x114, 0xf)   // row_shr:4
  DPPADD(0x118, 0xf)   // row_shr:8
  DPPADD(0x142, 0xa)   // row_bcast:15
  DPPADD(0x143, 0xc)   // row_bcast:31
#undef DPPADD
  return __builtin_bit_cast(
      float, __builtin_amdgcn_readlane(__builtin_bit_cast(int, v), 63));
}

// all-lanes sum within each 16-lane group, pure VALU (DPP).
__device__ __forceinline__ float group16_sum(float v) {
#define DPPADD(ctrl)                                                         \
  v += __builtin_bit_cast(float, __builtin_amdgcn_update_dpp(                \
           0, __builtin_bit_cast(int, v), ctrl, 0xf, 0xf, false));
  DPPADD(0xB1)    // quad_perm [1,0,3,2]  (xor 1)
  DPPADD(0x4E)    // quad_perm [2,3,0,1]  (xor 2)
  DPPADD(0x141)   // row_half_mirror
  DPPADD(0x140)   // row_mirror
#undef DPPADD
  return v;
}

// x2[i] = ||x_i||^2 (fp32, matches reference) + bf16 copy of data + flag reset.
__global__ void fcm_prep(const float* __restrict__ data, float* __restrict__ x2,
                         unsigned short* __restrict__ xbf,
                         float* __restrict__ diffac, int* __restrict__ done,
                         int* __restrict__ ticket, int N) {
  int i = blockIdx.x * blockDim.x + threadIdx.x;
  if (i == 0) { *diffac = 0.0f; *done = 0; *ticket = 0; }
  if (i < N) {
    const float4* r = (const float4*)(data + (size_t)i * DM);
    unsigned short* xo = xbf + (size_t)i * DM;
    float s = 0.0f;
#pragma unroll
    for (int q = 0; q < DM / 4; q++) {
      float4 v = r[q];
      s = fmaf(v.x, v.x, s); s = fmaf(v.y, v.y, s);
      s = fmaf(v.z, v.z, s); s = fmaf(v.w, v.w, s);
      uint2 pk = {pkbf(v.x, v.y), pkbf(v.z, v.w)};
      *(uint2*)(void*)(xo + q * 4) = pk;
    }
    x2[i] = s;
  }
}

// Fused pass. INIT: W := u0 (raw memberships). else: W := 1/dist via MFMA GEMM1.
// Both: um = (W * rr)^2 -> bf16 umT -> MFMA GEMM2 accumulate -> partial.
template <bool INIT>
__global__ __launch_bounds__(256, 3)
void fcm_pass(const unsigned short* __restrict__ xbf, const float* __restrict__ x2,
              const float* __restrict__ CU,   // INIT: u0[N][64]; else C[64][64]
              float* __restrict__ partial, const int* __restrict__ done,
              int N, int ntiles) {
  if (!INIT && *done) return;
  __shared__ __align__(16) unsigned short Xb[64 * LDP];   // X[p][d] bf16
  __shared__ __align__(16) unsigned short XTb[64 * LDP];  // X^T[d][p] bf16
  __shared__ __align__(16) unsigned short umT[64 * LDP];  // um^T[j][p] bf16
  __shared__ __align__(16) float rpart[4 * 64];           // per-wave rowsum partials
  __shared__ __align__(16) float rrs[64];                 // rcp(rowsum[p]), 0 if pad
  __shared__ __align__(16) float x2s[64];

  const int tid  = threadIdx.x;
  const int w    = __builtin_amdgcn_readfirstlane(tid >> 6);  // wave id: cluster tile
  const int col  = tid & 15;
  const int quad = (tid >> 4) & 3;

  // ---- per-kernel prep: C row j=16w+col -> c2[j] (fp32) + bf16 B-frags ----
  bf16x8 cf0, cf1;
  float c2j = 0.0f;
  if (!INIT) {
    const float* crow = CU + (size_t)(16 * w + col) * DM;
    float4 ca = *(const float4*)(crow + quad * 8);
    float4 cb = *(const float4*)(crow + quad * 8 + 4);
    float4 cc = *(const float4*)(crow + 32 + quad * 8);
    float4 cd = *(const float4*)(crow + 32 + quad * 8 + 4);
    float cp = ca.x*ca.x + ca.y*ca.y + ca.z*ca.z + ca.w*ca.w
             + cb.x*cb.x + cb.y*cb.y + cb.z*cb.z + cb.w*cb.w
             + cc.x*cc.x + cc.y*cc.y + cc.z*cc.z + cc.w*cc.w
             + cd.x*cd.x + cd.y*cd.y + cd.z*cd.z + cd.w*cd.w;
    cp += __shfl_xor(cp, 16, 64);
    cp += __shfl_xor(cp, 32, 64);
    c2j = cp;
    union { bf16x8 v; unsigned u[4]; } P0, P1;
    P0.u[0] = pkbf(ca.x, ca.y); P0.u[1] = pkbf(ca.z, ca.w);
    P0.u[2] = pkbf(cb.x, cb.y); P0.u[3] = pkbf(cb.z, cb.w);
    P1.u[0] = pkbf(cc.x, cc.y); P1.u[1] = pkbf(cc.z, cc.w);
    P1.u[2] = pkbf(cd.x, cd.y); P1.u[3] = pkbf(cd.z, cd.w);
    cf0 = P0.v; cf1 = P1.v;
  }

  // ones B-fragment: den[j] = sum_p umT[j][p] * 1 via MFMA (matrix pipe ~idle)
  union { bf16x8 v; unsigned u[4]; } ON;
  ON.u[0] = ON.u[1] = ON.u[2] = ON.u[3] = 0x3F803F80u;   // bf16 1.0 x2
  const bf16x8 onesf = ON.v;

  f32x4 D2[4];   // C-partial accumulator: tiles (jt=w, dt=0..3)
#pragma unroll
  for (int dt = 0; dt < 4; dt++) D2[dt] = f32x4{0.f, 0.f, 0.f, 0.f};
  f32x4 Dden = f32x4{0.f, 0.f, 0.f, 0.f};   // den[j=16w+quad*4+r], col-duplicated

  // ---- hoisted staging geometry (invariant per thread):
  // thread handles point sp, d-chunks sd0 and sd0+32. Scatter writes are
  // lane-consecutive in p (<=2 lanes/dword -> conflict-free-ish).
  const int sp  = tid & 63;
  const int sd0 = (tid >> 6) * 8;                         // 0/8/16/24 by wave
  const unsigned short* gsrc = xbf + (size_t)sp * DM + sd0;
  unsigned short* xw = &Xb[sp * LDP + sd0];
  unsigned short* xt = &XTb[sd0 * LDP + sp];

  for (int t = blockIdx.x; t < ntiles; t += gridDim.x) {
    const int base = t * 64;
    const int np = min(64, N - base);
    __syncthreads();   // previous iteration's LDS reads done

    // ---- staging: bf16 global -> Xb rows (b128) + XTb transpose (b16) ----
    {
      bf16x8 v0 = {0, 0, 0, 0, 0, 0, 0, 0};
      bf16x8 v1 = {0, 0, 0, 0, 0, 0, 0, 0};
      if (sp < np) {
        const unsigned short* g = gsrc + (size_t)base * DM;
        v0 = *(const bf16x8*)(g);
        v1 = *(const bf16x8*)(g + 32);
      }
      *(bf16x8*)(void*)xw = v0;
      *(bf16x8*)(void*)(xw + 32) = v1;
#pragma unroll
      for (int k = 0; k < 8; k++) xt[k * LDP] = (unsigned short)v0[k];
#pragma unroll
      for (int k = 0; k < 8; k++) xt[(k + 32) * LDP] = (unsigned short)v1[k];
    }
    if (tid < 64) x2s[tid] = (base + tid < N) ? x2[base + tid] : 0.0f;
    __syncthreads();

    // ---- W: either GEMM1 (1/dist) or u0 loads. lane view (MFMA C/D layout):
    //      value (p=pt*16+quad*4+r, j=16w+col) in Wv[pt][r]. ----
    f32x4 Wv[4];
    if (INIT) {
#pragma unroll
      for (int pt = 0; pt < 4; pt++) {
        f32x4 wv = {0.f, 0.f, 0.f, 0.f};
#pragma unroll
        for (int r = 0; r < 4; r++) {
          int pl = pt * 16 + quad * 4 + r;
          if (pl < np) wv[r] = CU[(size_t)(base + pl) * CL + 16 * w + col];
        }
        Wv[pt] = wv;
      }
    } else {
#pragma unroll
      for (int pt = 0; pt < 4; pt++) {
        bf16x8 a0 = *(const bf16x8*)(const void*)&Xb[(pt * 16 + col) * LDP + quad * 8];
        bf16x8 a1 = *(const bf16x8*)(const void*)&Xb[(pt * 16 + col) * LDP + 32 + quad * 8];
        f32x4 s = f32x4{0.f, 0.f, 0.f, 0.f};
        s = __builtin_amdgcn_mfma_f32_16x16x32_bf16(a0, cf0, s, 0, 0, 0);
        s = __builtin_amdgcn_mfma_f32_16x16x32_bf16(a1, cf1, s, 0, 0, 0);
        f32x4 x2v = *(const f32x4*)(const void*)&x2s[pt * 16 + quad * 4];
#pragma unroll
        for (int r = 0; r < 4; r++) {
          float dist = fmaxf(fmaf(-2.0f, s[r], x2v[r] + c2j), 0.0f);
          Wv[pt][r] = __builtin_amdgcn_rcpf(dist);   // d^(-p/2), p=2
        }
      }
    }

    // ---- rowsum over this wave's 16 clusters (DPP), cross-wave via LDS ----
#pragma unroll
    for (int pt = 0; pt < 4; pt++) {
      float r0 = group16_sum(Wv[pt][0]);
      float r1 = group16_sum(Wv[pt][1]);
      float r2 = group16_sum(Wv[pt][2]);
      float r3 = group16_sum(Wv[pt][3]);
      if (col == 0) {
        float4 v4 = {r0, r1, r2, r3};
        *(float4*)(void*)&rpart[w * 64 + pt * 16 + quad * 4] = v4;
      }
    }
    __syncthreads();
    if (tid < 64) {
      float rt = rpart[tid] + rpart[64 + tid] + rpart[128 + tid] + rpart[192 + tid];
      // pad mask lives HERE (per point, 1 cmp) -> um of padded p is exactly 0
      rrs[tid] = (base + tid < N) ? __builtin_amdgcn_rcpf(rt) : 0.0f;
    }
    __syncthreads();

    // ---- um = (W * rr)^2 -> bf16 umT write (hw cvt_pk) ----
#pragma unroll
    for (int pt = 0; pt < 4; pt++) {
      f32x4 rrv = *(const f32x4*)(const void*)&rrs[pt * 16 + quad * 4];
      f32x4 u = Wv[pt] * rrv;
      f32x4 m = u * u;
      uint2 pk = {cvtpk_bf16(m[0], m[1]), cvtpk_bf16(m[2], m[3])};
      *(uint2*)(void*)&umT[(16 * w + col) * LDP + pt * 16 + quad * 4] = pk;
    }
    // no barrier: each wave reads back only the umT rows it wrote (lgkmcnt order)

    // ---- GEMM2: D2[jt=w][dt] += um^T @ X ;  Dden += um^T @ ones ----
#pragma unroll
    for (int pb = 0; pb < 2; pb++) {
      bf16x8 au = *(const bf16x8*)(const void*)&umT[(16 * w + col) * LDP + pb * 32 + quad * 8];
      Dden = __builtin_amdgcn_mfma_f32_16x16x32_bf16(au, onesf, Dden, 0, 0, 0);
#pragma unroll
      for (int dt = 0; dt < 4; dt++) {
        bf16x8 bx = *(const bf16x8*)(const void*)&XTb[(dt * 16 + col) * LDP + pb * 32 + quad * 8];
        D2[dt] = __builtin_amdgcn_mfma_f32_16x16x32_bf16(au, bx, D2[dt], 0, 0, 0);
      }
    }
  }

  // ---- epilogue: write per-block partial (den from MFMA, col-duplicated) ----
  float* pbuf = partial + (size_t)blockIdx.x * PARTIAL_STRIDE;
  if (col == 0) {
    float4 dv = {Dden[0], Dden[1], Dden[2], Dden[3]};
    *(float4*)(void*)&pbuf[CL * DM + 16 * w + quad * 4] = dv;
  }
#pragma unroll
  for (int dt = 0; dt < 4; dt++)
#pragma unroll
    for (int r = 0; r < 4; r++)
      pbuf[(size_t)(16 * w + quad * 4 + r) * DM + dt * 16 + col] = D2[dt][r];
}

// Sum partials -> C_new; Frobenius diff; last block (ticket) does convergence check.
__global__ __launch_bounds__(1024, 1)
void fcm_reduce(const float* __restrict__ partial, float* __restrict__ Cnew,
                const float* __restrict__ Cold, float* __restrict__ out,
                float* __restrict__ diffac, int* __restrict__ done,
                int* __restrict__ ticket, int compute_diff, int nb) {
  if (compute_diff && *done) return;
  __shared__ float sm[16 * 64];
  __shared__ float sden[1024];
  __shared__ int lastflag;
  __shared__ float sdiff;
  int j = blockIdx.x;
  int tid = threadIdx.x;
  int d = tid & 63;
  int slice = tid >> 6;
  float s = 0.0f;
  for (int b = slice; b < nb; b += 16)
    s += partial[(size_t)b * PARTIAL_STRIDE + j * DM + d];
  sm[slice * 64 + d] = s;
  float dv = 0.0f;
  for (int b = tid; b < nb; b += 1024)
    dv += partial[(size_t)b * PARTIAL_STRIDE + CL * DM + j];
  sden[tid] = dv;
  __syncthreads();
#pragma unroll
  for (int st = 8; st; st >>= 1) {
    if (slice < st) sm[slice * 64 + d] += sm[(slice + st) * 64 + d];
    __syncthreads();
  }
#pragma unroll
  for (int st = 512; st >= 64; st >>= 1) {
    if (tid < st) sden[tid] += sden[tid + st];
    __syncthreads();
  }
  if (tid < 64) {
    float denj = wave_sum(sden[tid]);
    float c = sm[tid] / denj;
    Cnew[j * DM + tid] = c;
    if (compute_diff) {
      float df = c - Cold[j * DM + tid];
      float tot = wave_sum(df * df);
      if (tid == 0) atomicAdd(diffac, tot);
    }
  }
  if (!compute_diff) return;
  __syncthreads();
  if (tid == 0) {
    __threadfence();
    int t = atomicAdd(ticket, 1);
    lastflag = (t == (int)gridDim.x - 1);
  }
  __syncthreads();
  if (!lastflag) return;
  if (tid == 0) sdiff = atomicAdd(diffac, 0.0f);
  __syncthreads();
  if (sdiff < 1e-16f) {                 // diff < 1e-8  <=>  diff^2 < 1e-16
    for (int i = tid; i < CL * DM; i += 1024) out[i] = Cold[i];
    if (tid == 0) *done = 1;
  }
  if (tid == 0) { *diffac = 0.0f; *ticket = 0; }
}

// If never converged, V = C_25.
__global__ void fcm_final(const float* __restrict__ Clast, float* __restrict__ out,
                          const int* __restrict__ done) {
  if (*done) return;
  int i = blockIdx.x * blockDim.x + threadIdx.x;
  if (i < CL * DM) out[i] = Clast[i];
}

extern "C" void kernel_launch(void* const* d_in, const int* in_sizes, int n_in,
                              void* d_out, int out_size, void* d_ws, size_t ws_size,
                              hipStream_t stream) {
  const float* data = (const float*)d_in[0];
  const float* u0   = (const float*)d_in[1];
  float* out = (float*)d_out;
  int N = in_sizes[0] / DM;            // 300000
  int ntiles = (N + 63) / 64;          // 4688

  float* ws = (float*)d_ws;
  size_t Noff = ((size_t)N + 15) & ~(size_t)15;
  float* x2 = ws;                                  // N fp32
  unsigned short* xbf = (unsigned short*)(ws + Noff);  // N*64 bf16 = N*32 float slots
  float* C0 = ws + Noff + (size_t)N * 32;
  float* C1 = C0 + CL * DM;
  float* diffac = C1 + CL * DM;
  int* done = (int*)(diffac + 1);
  int* ticket = (int*)(diffac + 2);
  float* partial = diffac + 16;

  size_t used = Noff + (size_t)N * 32 + 2 * CL * DM + 16;
  size_t avail = (ws_size / 4 > used) ? (ws_size / 4 - used) / PARTIAL_STRIDE : 0;
  int nb = (int)(avail < MAX_BLOCKS ? avail : MAX_BLOCKS);
  if (nb < 1) nb = 1;

  hipLaunchKernelGGL(fcm_prep, dim3((N + 255) / 256), dim3(256), 0, stream,
                     data, x2, xbf, diffac, done, ticket, N);
  hipLaunchKernelGGL((fcm_pass<true>), dim3(nb), dim3(256), 0, stream,
                     xbf, x2, u0, partial, done, N, ntiles);
  hipLaunchKernelGGL(fcm_reduce, dim3(64), dim3(1024), 0, stream,
                     partial, C0, C1, out, diffac, done, ticket, 0, nb);

  float* bufs[2] = {C0, C1};
  for (int k = 0; k < MAX_ITER; k++) {
    float* Cc = bufs[k & 1];
    float* Cn = bufs[(k + 1) & 1];
    hipLaunchKernelGGL((fcm_pass<false>), dim3(nb), dim3(256), 0, stream,
                       xbf, x2, Cc, partial, done, N, ntiles);
    hipLaunchKernelGGL(fcm_reduce, dim3(64), dim3(1024), 0, stream,
                       partial, Cn, Cc, out, diffac, done, ticket, 1, nb);
  }
  hipLaunchKernelGGL(fcm_final, dim3(16), dim3(256), 0, stream,
                     bufs[1], out, done);
}

// Round 2
// 389.607 us; speedup vs baseline: 1.0983x; 1.0294x over previous
//
#include <hip/hip_runtime.h>

// Fuzzy c-means on MI355X. N=300000, D=64, c=64, m=2 (p=2), 25 updates + init.
// R4: MFMA rewrite (432us). R5: bf16 xbf copy, nb=512 (427us).
// R6: VALU cuts in pass (cvt_pk, per-point pad mask, MFMA den) + conflict-free
//     staging scatter (401us).
// R7: prep was 49us at 2.2TB/s -- per-thread row-walk was uncoalesced. Now
//     one float4/lane (1KB/wave coalesced), row x2 via 16-lane DPP sum.
//     MAX_BLOCKS 512->768: pass grid was capping occupancy at 2 blocks/CU.

#define DM 64
#define CL 64
#define PARTIAL_STRIDE 4160      // 64*64 num + 64 den
#define MAX_ITER 25
#define MAX_BLOCKS 768
#define LDP 72                   // padded row length (bf16) for Xb/XTb/umT

typedef __attribute__((ext_vector_type(8))) short bf16x8;   // MFMA A/B frag (4 VGPRs)
typedef __attribute__((ext_vector_type(4))) float f32x4;    // MFMA C/D frag

__device__ __forceinline__ unsigned f2bf1(float f) {        // fp32 -> bf16 (RNE)
  unsigned u = __builtin_bit_cast(unsigned, f);
  return (u + 0x7FFFu + ((u >> 16) & 1u)) >> 16;
}
__device__ __forceinline__ unsigned pkbf(float a, float b) {
  return f2bf1(a) | (f2bf1(b) << 16);
}
// HW packed fp32->2xbf16 (RNE), gfx950. %1 -> low half, %2 -> high half.
__device__ __forceinline__ unsigned cvtpk_bf16(float a, float b) {
  unsigned r;
  asm("v_cvt_pk_bf16_f32 %0, %1, %2" : "=v"(r) : "v"(a), "v"(b));
  return r;
}

// 64-lane sum (reduce kernel only): DPP row reduce + bcast, result via lane 63.
__device__ __forceinline__ float wave_sum(float v) {
#define DPPADD(ctrl, rmask)                                                  \
  v += __builtin_bit_cast(float, __builtin_amdgcn_update_dpp(                \
           0, __builtin_bit_cast(int, v), ctrl, rmask, 0xf, false));
  DPPADD(0x111, 0xf)   // row_shr:1
  DPPADD(0x112, 0xf)   // row_shr:2
  DPPADD(0x114, 0xf)   // row_shr:4
  DPPADD(0x118, 0xf)   // row_shr:8
  DPPADD(0x142, 0xa)   // row_bcast:15
  DPPADD(0x143, 0xc)   // row_bcast:31
#undef DPPADD
  return __builtin_bit_cast(
      float, __builtin_amdgcn_readlane(__builtin_bit_cast(int, v), 63));
}

// all-lanes sum within each 16-lane group, pure VALU (DPP).
__device__ __forceinline__ float group16_sum(float v) {
#define DPPADD(ctrl)                                                         \
  v += __builtin_bit_cast(float, __builtin_amdgcn_update_dpp(                \
           0, __builtin_bit_cast(int, v), ctrl, 0xf, 0xf, false));
  DPPADD(0xB1)    // quad_perm [1,0,3,2]  (xor 1)
  DPPADD(0x4E)    // quad_perm [2,3,0,1]  (xor 2)
  DPPADD(0x141)   // row_half_mirror
  DPPADD(0x140)   // row_mirror
#undef DPPADD
  return v;
}

// Coalesced prep: one float4 per lane, 16 lanes = one data row.
// x2[i] = ||x_i||^2 via DPP 16-lane sum; bf16 copy via hw cvt_pk; flag reset.
__global__ __launch_bounds__(256)
void fcm_prep(const float* __restrict__ data, float* __restrict__ x2,
              unsigned short* __restrict__ xbf,
              float* __restrict__ diffac, int* __restrict__ done,
              int* __restrict__ ticket, int N) {
  size_t i = (size_t)blockIdx.x * blockDim.x + threadIdx.x;   // float4 index
  if (i == 0) { *diffac = 0.0f; *done = 0; *ticket = 0; }
  size_t nvec = (size_t)N * (DM / 4);
  if (i >= nvec) return;                 // rows are 16 vecs: groups all-in/all-out
  float4 v = ((const float4*)data)[i];
  float s = fmaf(v.x, v.x, fmaf(v.y, v.y, fmaf(v.z, v.z, v.w * v.w)));
  float rs = group16_sum(s);             // row sum across the 16-lane group
  if ((threadIdx.x & 15) == 0) x2[i >> 4] = rs;
  uint2 pk = {cvtpk_bf16(v.x, v.y), cvtpk_bf16(v.z, v.w)};
  ((uint2*)xbf)[i] = pk;
}

// Fused pass. INIT: W := u0 (raw memberships). else: W := 1/dist via MFMA GEMM1.
// Both: um = (W * rr)^2 -> bf16 umT -> MFMA GEMM2 accumulate -> partial.
template <bool INIT>
__global__ __launch_bounds__(256, 3)
void fcm_pass(const unsigned short* __restrict__ xbf, const float* __restrict__ x2,
              const float* __restrict__ CU,   // INIT: u0[N][64]; else C[64][64]
              float* __restrict__ partial, const int* __restrict__ done,
              int N, int ntiles) {
  if (!INIT && *done) return;
  __shared__ __align__(16) unsigned short Xb[64 * LDP];   // X[p][d] bf16
  __shared__ __align__(16) unsigned short XTb[64 * LDP];  // X^T[d][p] bf16
  __shared__ __align__(16) unsigned short umT[64 * LDP];  // um^T[j][p] bf16
  __shared__ __align__(16) float rpart[4 * 64];           // per-wave rowsum partials
  __shared__ __align__(16) float rrs[64];                 // rcp(rowsum[p]), 0 if pad
  __shared__ __align__(16) float x2s[64];

  const int tid  = threadIdx.x;
  const int w    = __builtin_amdgcn_readfirstlane(tid >> 6);  // wave id: cluster tile
  const int col  = tid & 15;
  const int quad = (tid >> 4) & 3;

  // ---- per-kernel prep: C row j=16w+col -> c2[j] (fp32) + bf16 B-frags ----
  bf16x8 cf0, cf1;
  float c2j = 0.0f;
  if (!INIT) {
    const float* crow = CU + (size_t)(16 * w + col) * DM;
    float4 ca = *(const float4*)(crow + quad * 8);
    float4 cb = *(const float4*)(crow + quad * 8 + 4);
    float4 cc = *(const float4*)(crow + 32 + quad * 8);
    float4 cd = *(const float4*)(crow + 32 + quad * 8 + 4);
    float cp = ca.x*ca.x + ca.y*ca.y + ca.z*ca.z + ca.w*ca.w
             + cb.x*cb.x + cb.y*cb.y + cb.z*cb.z + cb.w*cb.w
             + cc.x*cc.x + cc.y*cc.y + cc.z*cc.z + cc.w*cc.w
             + cd.x*cd.x + cd.y*cd.y + cd.z*cd.z + cd.w*cd.w;
    cp += __shfl_xor(cp, 16, 64);
    cp += __shfl_xor(cp, 32, 64);
    c2j = cp;
    union { bf16x8 v; unsigned u[4]; } P0, P1;
    P0.u[0] = pkbf(ca.x, ca.y); P0.u[1] = pkbf(ca.z, ca.w);
    P0.u[2] = pkbf(cb.x, cb.y); P0.u[3] = pkbf(cb.z, cb.w);
    P1.u[0] = pkbf(cc.x, cc.y); P1.u[1] = pkbf(cc.z, cc.w);
    P1.u[2] = pkbf(cd.x, cd.y); P1.u[3] = pkbf(cd.z, cd.w);
    cf0 = P0.v; cf1 = P1.v;
  }

  // ones B-fragment: den[j] = sum_p umT[j][p] * 1 via MFMA (matrix pipe ~idle)
  union { bf16x8 v; unsigned u[4]; } ON;
  ON.u[0] = ON.u[1] = ON.u[2] = ON.u[3] = 0x3F803F80u;   // bf16 1.0 x2
  const bf16x8 onesf = ON.v;

  f32x4 D2[4];   // C-partial accumulator: tiles (jt=w, dt=0..3)
#pragma unroll
  for (int dt = 0; dt < 4; dt++) D2[dt] = f32x4{0.f, 0.f, 0.f, 0.f};
  f32x4 Dden = f32x4{0.f, 0.f, 0.f, 0.f};   // den[j=16w+quad*4+r], col-duplicated

  // ---- hoisted staging geometry (invariant per thread):
  // thread handles point sp, d-chunks sd0 and sd0+32. Scatter writes are
  // lane-consecutive in p (<=2 lanes/dword -> conflict-free-ish).
  const int sp  = tid & 63;
  const int sd0 = (tid >> 6) * 8;                         // 0/8/16/24 by wave
  const unsigned short* gsrc = xbf + (size_t)sp * DM + sd0;
  unsigned short* xw = &Xb[sp * LDP + sd0];
  unsigned short* xt = &XTb[sd0 * LDP + sp];

  for (int t = blockIdx.x; t < ntiles; t += gridDim.x) {
    const int base = t * 64;
    const int np = min(64, N - base);
    __syncthreads();   // previous iteration's LDS reads done

    // ---- staging: bf16 global -> Xb rows (b128) + XTb transpose (b16) ----
    {
      bf16x8 v0 = {0, 0, 0, 0, 0, 0, 0, 0};
      bf16x8 v1 = {0, 0, 0, 0, 0, 0, 0, 0};
      if (sp < np) {
        const unsigned short* g = gsrc + (size_t)base * DM;
        v0 = *(const bf16x8*)(g);
        v1 = *(const bf16x8*)(g + 32);
      }
      *(bf16x8*)(void*)xw = v0;
      *(bf16x8*)(void*)(xw + 32) = v1;
#pragma unroll
      for (int k = 0; k < 8; k++) xt[k * LDP] = (unsigned short)v0[k];
#pragma unroll
      for (int k = 0; k < 8; k++) xt[(k + 32) * LDP] = (unsigned short)v1[k];
    }
    if (tid < 64) x2s[tid] = (base + tid < N) ? x2[base + tid] : 0.0f;
    __syncthreads();

    // ---- W: either GEMM1 (1/dist) or u0 loads. lane view (MFMA C/D layout):
    //      value (p=pt*16+quad*4+r, j=16w+col) in Wv[pt][r]. ----
    f32x4 Wv[4];
    if (INIT) {
#pragma unroll
      for (int pt = 0; pt < 4; pt++) {
        f32x4 wv = {0.f, 0.f, 0.f, 0.f};
#pragma unroll
        for (int r = 0; r < 4; r++) {
          int pl = pt * 16 + quad * 4 + r;
          if (pl < np) wv[r] = CU[(size_t)(base + pl) * CL + 16 * w + col];
        }
        Wv[pt] = wv;
      }
    } else {
#pragma unroll
      for (int pt = 0; pt < 4; pt++) {
        bf16x8 a0 = *(const bf16x8*)(const void*)&Xb[(pt * 16 + col) * LDP + quad * 8];
        bf16x8 a1 = *(const bf16x8*)(const void*)&Xb[(pt * 16 + col) * LDP + 32 + quad * 8];
        f32x4 s = f32x4{0.f, 0.f, 0.f, 0.f};
        s = __builtin_amdgcn_mfma_f32_16x16x32_bf16(a0, cf0, s, 0, 0, 0);
        s = __builtin_amdgcn_mfma_f32_16x16x32_bf16(a1, cf1, s, 0, 0, 0);
        f32x4 x2v = *(const f32x4*)(const void*)&x2s[pt * 16 + quad * 4];
#pragma unroll
        for (int r = 0; r < 4; r++) {
          float dist = fmaxf(fmaf(-2.0f, s[r], x2v[r] + c2j), 0.0f);
          Wv[pt][r] = __builtin_amdgcn_rcpf(dist);   // d^(-p/2), p=2
        }
      }
    }

    // ---- rowsum over this wave's 16 clusters (DPP), cross-wave via LDS ----
#pragma unroll
    for (int pt = 0; pt < 4; pt++) {
      float r0 = group16_sum(Wv[pt][0]);
      float r1 = group16_sum(Wv[pt][1]);
      float r2 = group16_sum(Wv[pt][2]);
      float r3 = group16_sum(Wv[pt][3]);
      if (col == 0) {
        float4 v4 = {r0, r1, r2, r3};
        *(float4*)(void*)&rpart[w * 64 + pt * 16 + quad * 4] = v4;
      }
    }
    __syncthreads();
    if (tid < 64) {
      float rt = rpart[tid] + rpart[64 + tid] + rpart[128 + tid] + rpart[192 + tid];
      // pad mask lives HERE (per point, 1 cmp) -> um of padded p is exactly 0
      rrs[tid] = (base + tid < N) ? __builtin_amdgcn_rcpf(rt) : 0.0f;
    }
    __syncthreads();

    // ---- um = (W * rr)^2 -> bf16 umT write (hw cvt_pk) ----
#pragma unroll
    for (int pt = 0; pt < 4; pt++) {
      f32x4 rrv = *(const f32x4*)(const void*)&rrs[pt * 16 + quad * 4];
      f32x4 u = Wv[pt] * rrv;
      f32x4 m = u * u;
      uint2 pk = {cvtpk_bf16(m[0], m[1]), cvtpk_bf16(m[2], m[3])};
      *(uint2*)(void*)&umT[(16 * w + col) * LDP + pt * 16 + quad * 4] = pk;
    }
    // no barrier: each wave reads back only the umT rows it wrote (lgkmcnt order)

    // ---- GEMM2: D2[jt=w][dt] += um^T @ X ;  Dden += um^T @ ones ----
#pragma unroll
    for (int pb = 0; pb < 2; pb++) {
      bf16x8 au = *(const bf16x8*)(const void*)&umT[(16 * w + col) * LDP + pb * 32 + quad * 8];
      Dden = __builtin_amdgcn_mfma_f32_16x16x32_bf16(au, onesf, Dden, 0, 0, 0);
#pragma unroll
      for (int dt = 0; dt < 4; dt++) {
        bf16x8 bx = *(const bf16x8*)(const void*)&XTb[(dt * 16 + col) * LDP + pb * 32 + quad * 8];
        D2[dt] = __builtin_amdgcn_mfma_f32_16x16x32_bf16(au, bx, D2[dt], 0, 0, 0);
      }
    }
  }

  // ---- epilogue: write per-block partial (den from MFMA, col-duplicated) ----
  float* pbuf = partial + (size_t)blockIdx.x * PARTIAL_STRIDE;
  if (col == 0) {
    float4 dv = {Dden[0], Dden[1], Dden[2], Dden[3]};
    *(float4*)(void*)&pbuf[CL * DM + 16 * w + quad * 4] = dv;
  }
#pragma unroll
  for (int dt = 0; dt < 4; dt++)
#pragma unroll
    for (int r = 0; r < 4; r++)
      pbuf[(size_t)(16 * w + quad * 4 + r) * DM + dt * 16 + col] = D2[dt][r];
}

// Sum partials -> C_new; Frobenius diff; last block (ticket) does convergence check.
__global__ __launch_bounds__(1024, 1)
void fcm_reduce(const float* __restrict__ partial, float* __restrict__ Cnew,
                const float* __restrict__ Cold, float* __restrict__ out,
                float* __restrict__ diffac, int* __restrict__ done,
                int* __restrict__ ticket, int compute_diff, int nb) {
  if (compute_diff && *done) return;
  __shared__ float sm[16 * 64];
  __shared__ float sden[1024];
  __shared__ int lastflag;
  __shared__ float sdiff;
  int j = blockIdx.x;
  int tid = threadIdx.x;
  int d = tid & 63;
  int slice = tid >> 6;
  float s = 0.0f;
  for (int b = slice; b < nb; b += 16)
    s += partial[(size_t)b * PARTIAL_STRIDE + j * DM + d];
  sm[slice * 64 + d] = s;
  float dv = 0.0f;
  for (int b = tid; b < nb; b += 1024)
    dv += partial[(size_t)b * PARTIAL_STRIDE + CL * DM + j];
  sden[tid] = dv;
  __syncthreads();
#pragma unroll
  for (int st = 8; st; st >>= 1) {
    if (slice < st) sm[slice * 64 + d] += sm[(slice + st) * 64 + d];
    __syncthreads();
  }
#pragma unroll
  for (int st = 512; st >= 64; st >>= 1) {
    if (tid < st) sden[tid] += sden[tid + st];
    __syncthreads();
  }
  if (tid < 64) {
    float denj = wave_sum(sden[tid]);
    float c = sm[tid] / denj;
    Cnew[j * DM + tid] = c;
    if (compute_diff) {
      float df = c - Cold[j * DM + tid];
      float tot = wave_sum(df * df);
      if (tid == 0) atomicAdd(diffac, tot);
    }
  }
  if (!compute_diff) return;
  __syncthreads();
  if (tid == 0) {
    __threadfence();
    int t = atomicAdd(ticket, 1);
    lastflag = (t == (int)gridDim.x - 1);
  }
  __syncthreads();
  if (!lastflag) return;
  if (tid == 0) sdiff = atomicAdd(diffac, 0.0f);
  __syncthreads();
  if (sdiff < 1e-16f) {                 // diff < 1e-8  <=>  diff^2 < 1e-16
    for (int i = tid; i < CL * DM; i += 1024) out[i] = Cold[i];
    if (tid == 0) *done = 1;
  }
  if (tid == 0) { *diffac = 0.0f; *ticket = 0; }
}

// If never converged, V = C_25.
__global__ void fcm_final(const float* __restrict__ Clast, float* __restrict__ out,
                          const int* __restrict__ done) {
  if (*done) return;
  int i = blockIdx.x * blockDim.x + threadIdx.x;
  if (i < CL * DM) out[i] = Clast[i];
}

extern "C" void kernel_launch(void* const* d_in, const int* in_sizes, int n_in,
                              void* d_out, int out_size, void* d_ws, size_t ws_size,
                              hipStream_t stream) {
  const float* data = (const float*)d_in[0];
  const float* u0   = (const float*)d_in[1];
  float* out = (float*)d_out;
  int N = in_sizes[0] / DM;            // 300000
  int ntiles = (N + 63) / 64;          // 4688

  float* ws = (float*)d_ws;
  size_t Noff = ((size_t)N + 15) & ~(size_t)15;
  float* x2 = ws;                                  // N fp32
  unsigned short* xbf = (unsigned short*)(ws + Noff);  // N*64 bf16 = N*32 float slots
  float* C0 = ws + Noff + (size_t)N * 32;
  float* C1 = C0 + CL * DM;
  float* diffac = C1 + CL * DM;
  int* done = (int*)(diffac + 1);
  int* ticket = (int*)(diffac + 2);
  float* partial = diffac + 16;

  size_t used = Noff + (size_t)N * 32 + 2 * CL * DM + 16;
  size_t avail = (ws_size / 4 > used) ? (ws_size / 4 - used) / PARTIAL_STRIDE : 0;
  int nb = (int)(avail < MAX_BLOCKS ? avail : MAX_BLOCKS);
  if (nb < 1) nb = 1;

  size_t nvec = (size_t)N * (DM / 4);
  hipLaunchKernelGGL(fcm_prep, dim3((unsigned)((nvec + 255) / 256)), dim3(256), 0,
                     stream, data, x2, xbf, diffac, done, ticket, N);
  hipLaunchKernelGGL((fcm_pass<true>), dim3(nb), dim3(256), 0, stream,
                     xbf, x2, u0, partial, done, N, ntiles);
  hipLaunchKernelGGL(fcm_reduce, dim3(64), dim3(1024), 0, stream,
                     partial, C0, C1, out, diffac, done, ticket, 0, nb);

  float* bufs[2] = {C0, C1};
  for (int k = 0; k < MAX_ITER; k++) {
    float* Cc = bufs[k & 1];
    float* Cn = bufs[(k + 1) & 1];
    hipLaunchKernelGGL((fcm_pass<false>), dim3(nb), dim3(256), 0, stream,
                       xbf, x2, Cc, partial, done, N, ntiles);
    hipLaunchKernelGGL(fcm_reduce, dim3(64), dim3(1024), 0, stream,
                       partial, Cn, Cc, out, diffac, done, ticket, 1, nb);
  }
  hipLaunchKernelGGL(fcm_final, dim3(16), dim3(256), 0, stream,
                     bufs[1], out, done);
}

// Round 3
// 387.550 us; speedup vs baseline: 1.1041x; 1.0053x over previous
//
#include <hip/hip_runtime.h>

// Fuzzy c-means on MI355X. N=300000, D=64, c=64, m=2 (p=2), 25 updates + init.
// R4: MFMA rewrite (432us). R5: bf16 xbf copy (427us). R6: VALU cuts + clean
// staging scatter (401us). R7: coalesced prep, nb=768 (390us).
// R8: GEMM1 re-decomposed per-wave-POINTS (wave holds B-frags for all 64
// clusters, +32 VGPR): rowsum is now in-register (3 adds + group16), the
// rpart/rrs LDS stage and 2 of 4 barriers are gone, A-frags read once
// (8->2 ds_read_b128/tile). One new barrier before GEMM2 (umT cross-wave).

#define DM 64
#define CL 64
#define PARTIAL_STRIDE 4160      // 64*64 num + 64 den
#define MAX_ITER 25
#define MAX_BLOCKS 768
#define LDP 72                   // padded row length (bf16) for Xb/XTb/umT

typedef __attribute__((ext_vector_type(8))) short bf16x8;   // MFMA A/B frag (4 VGPRs)
typedef __attribute__((ext_vector_type(4))) float f32x4;    // MFMA C/D frag

__device__ __forceinline__ unsigned f2bf1(float f) {        // fp32 -> bf16 (RNE)
  unsigned u = __builtin_bit_cast(unsigned, f);
  return (u + 0x7FFFu + ((u >> 16) & 1u)) >> 16;
}
__device__ __forceinline__ unsigned pkbf(float a, float b) {
  return f2bf1(a) | (f2bf1(b) << 16);
}
// HW packed fp32->2xbf16 (RNE), gfx950. %1 -> low half, %2 -> high half.
__device__ __forceinline__ unsigned cvtpk_bf16(float a, float b) {
  unsigned r;
  asm("v_cvt_pk_bf16_f32 %0, %1, %2" : "=v"(r) : "v"(a), "v"(b));
  return r;
}

// 64-lane sum (reduce kernel only): DPP row reduce + bcast, result via lane 63.
__device__ __forceinline__ float wave_sum(float v) {
#define DPPADD(ctrl, rmask)                                                  \
  v += __builtin_bit_cast(float, __builtin_amdgcn_update_dpp(                \
           0, __builtin_bit_cast(int, v), ctrl, rmask, 0xf, false));
  DPPADD(0x111, 0xf)   // row_shr:1
  DPPADD(0x112, 0xf)   // row_shr:2
  DPPADD(0x114, 0xf)   // row_shr:4
  DPPADD(0x118, 0xf)   // row_shr:8
  DPPADD(0x142, 0xa)   // row_bcast:15
  DPPADD(0x143, 0xc)   // row_bcast:31
#undef DPPADD
  return __builtin_bit_cast(
      float, __builtin_amdgcn_readlane(__builtin_bit_cast(int, v), 63));
}

// all-lanes sum within each 16-lane group, pure VALU (DPP).
__device__ __forceinline__ float group16_sum(float v) {
#define DPPADD(ctrl)                                                         \
  v += __builtin_bit_cast(float, __builtin_amdgcn_update_dpp(                \
           0, __builtin_bit_cast(int, v), ctrl, 0xf, 0xf, false));
  DPPADD(0xB1)    // quad_perm [1,0,3,2]  (xor 1)
  DPPADD(0x4E)    // quad_perm [2,3,0,1]  (xor 2)
  DPPADD(0x141)   // row_half_mirror
  DPPADD(0x140)   // row_mirror
#undef DPPADD
  return v;
}

// Coalesced prep: one float4 per lane, 16 lanes = one data row.
// x2[i] = ||x_i||^2 via DPP 16-lane sum; bf16 copy via hw cvt_pk; flag reset.
__global__ __launch_bounds__(256)
void fcm_prep(const float* __restrict__ data, float* __restrict__ x2,
              unsigned short* __restrict__ xbf,
              float* __restrict__ diffac, int* __restrict__ done,
              int* __restrict__ ticket, int N) {
  size_t i = (size_t)blockIdx.x * blockDim.x + threadIdx.x;   // float4 index
  if (i == 0) { *diffac = 0.0f; *done = 0; *ticket = 0; }
  size_t nvec = (size_t)N * (DM / 4);
  if (i >= nvec) return;                 // rows are 16 vecs: groups all-in/all-out
  float4 v = ((const float4*)data)[i];
  float s = fmaf(v.x, v.x, fmaf(v.y, v.y, fmaf(v.z, v.z, v.w * v.w)));
  float rs = group16_sum(s);             // row sum across the 16-lane group
  if ((threadIdx.x & 15) == 0) x2[i >> 4] = rs;
  uint2 pk = {cvtpk_bf16(v.x, v.y), cvtpk_bf16(v.z, v.w)};
  ((uint2*)xbf)[i] = pk;
}

// Fused pass. INIT: W := u0 (raw memberships). else: W := 1/dist via MFMA GEMM1.
// Wave w owns points p in [16w,16w+16) and ALL 64 clusters (B-frags in regs).
// um = (W * rr)^2 -> bf16 umT -> barrier -> MFMA GEMM2 accumulate -> partial.
template <bool INIT>
__global__ __launch_bounds__(256, 3)
void fcm_pass(const unsigned short* __restrict__ xbf, const float* __restrict__ x2,
              const float* __restrict__ CU,   // INIT: u0[N][64]; else C[64][64]
              float* __restrict__ partial, const int* __restrict__ done,
              int N, int ntiles) {
  if (!INIT && *done) return;
  __shared__ __align__(16) unsigned short Xb[64 * LDP];   // X[p][d] bf16
  __shared__ __align__(16) unsigned short XTb[64 * LDP];  // X^T[d][p] bf16
  __shared__ __align__(16) unsigned short umT[64 * LDP];  // um^T[j][p] bf16
  __shared__ __align__(16) float x2s[64];

  const int tid  = threadIdx.x;
  const int w    = __builtin_amdgcn_readfirstlane(tid >> 6);  // wave id: POINT tile
  const int col  = tid & 15;
  const int quad = (tid >> 4) & 3;

  // ---- per-kernel prep: ALL 4 j-tiles' C rows -> c2v[jt] + bf16 B-frags ----
  bf16x8 cf0[4], cf1[4];
  float c2v[4];
  if (!INIT) {
#pragma unroll
    for (int jt = 0; jt < 4; jt++) {
      const float* crow = CU + (size_t)(16 * jt + col) * DM;
      float4 ca = *(const float4*)(crow + quad * 8);
      float4 cb = *(const float4*)(crow + quad * 8 + 4);
      float4 cc = *(const float4*)(crow + 32 + quad * 8);
      float4 cd = *(const float4*)(crow + 32 + quad * 8 + 4);
      float cp = ca.x*ca.x + ca.y*ca.y + ca.z*ca.z + ca.w*ca.w
               + cb.x*cb.x + cb.y*cb.y + cb.z*cb.z + cb.w*cb.w
               + cc.x*cc.x + cc.y*cc.y + cc.z*cc.z + cc.w*cc.w
               + cd.x*cd.x + cd.y*cd.y + cd.z*cd.z + cd.w*cd.w;
      cp += __shfl_xor(cp, 16, 64);
      cp += __shfl_xor(cp, 32, 64);
      c2v[jt] = cp;
      union { bf16x8 v; unsigned u[4]; } P0, P1;
      P0.u[0] = pkbf(ca.x, ca.y); P0.u[1] = pkbf(ca.z, ca.w);
      P0.u[2] = pkbf(cb.x, cb.y); P0.u[3] = pkbf(cb.z, cb.w);
      P1.u[0] = pkbf(cc.x, cc.y); P1.u[1] = pkbf(cc.z, cc.w);
      P1.u[2] = pkbf(cd.x, cd.y); P1.u[3] = pkbf(cd.z, cd.w);
      cf0[jt] = P0.v; cf1[jt] = P1.v;
    }
  }

  // ones B-fragment: den[j] = sum_p umT[j][p] * 1 via MFMA (matrix pipe ~idle)
  union { bf16x8 v; unsigned u[4]; } ON;
  ON.u[0] = ON.u[1] = ON.u[2] = ON.u[3] = 0x3F803F80u;   // bf16 1.0 x2
  const bf16x8 onesf = ON.v;

  f32x4 D2[4];   // C-partial accumulator: output j-tile = w, dt=0..3
#pragma unroll
  for (int dt = 0; dt < 4; dt++) D2[dt] = f32x4{0.f, 0.f, 0.f, 0.f};
  f32x4 Dden = f32x4{0.f, 0.f, 0.f, 0.f};   // den[j=16w+quad*4+r], col-duplicated

  // ---- hoisted staging geometry (invariant per thread) ----
  const int sp  = tid & 63;
  const int sd0 = (tid >> 6) * 8;                         // 0/8/16/24 by wave
  const unsigned short* gsrc = xbf + (size_t)sp * DM + sd0;
  unsigned short* xw = &Xb[sp * LDP + sd0];
  unsigned short* xt = &XTb[sd0 * LDP + sp];

  for (int t = blockIdx.x; t < ntiles; t += gridDim.x) {
    const int base = t * 64;
    const int np = min(64, N - base);
    __syncthreads();   // previous iteration's LDS reads done

    // ---- staging: bf16 global -> Xb rows (b128) + XTb transpose (b16) ----
    {
      bf16x8 v0 = {0, 0, 0, 0, 0, 0, 0, 0};
      bf16x8 v1 = {0, 0, 0, 0, 0, 0, 0, 0};
      if (sp < np) {
        const unsigned short* g = gsrc + (size_t)base * DM;
        v0 = *(const bf16x8*)(g);
        v1 = *(const bf16x8*)(g + 32);
      }
      *(bf16x8*)(void*)xw = v0;
      *(bf16x8*)(void*)(xw + 32) = v1;
#pragma unroll
      for (int k = 0; k < 8; k++) xt[k * LDP] = (unsigned short)v0[k];
#pragma unroll
      for (int k = 0; k < 8; k++) xt[(k + 32) * LDP] = (unsigned short)v1[k];
    }
    if (tid < 64) x2s[tid] = (base + tid < N) ? x2[base + tid] : 0.0f;
    __syncthreads();

    // ---- W[jt][r] for p = 16w+quad*4+r, j = 16jt+col ----
    float Wv[4][4];
    if (INIT) {
#pragma unroll
      for (int jt = 0; jt < 4; jt++)
#pragma unroll
        for (int r = 0; r < 4; r++) {
          int pl = 16 * w + quad * 4 + r;
          Wv[jt][r] = (pl < np)
              ? CU[(size_t)(base + pl) * CL + 16 * jt + col] : 0.0f;
        }
    } else {
      bf16x8 a0 = *(const bf16x8*)(const void*)&Xb[(16 * w + col) * LDP + quad * 8];
      bf16x8 a1 = *(const bf16x8*)(const void*)&Xb[(16 * w + col) * LDP + 32 + quad * 8];
      f32x4 x2p = *(const f32x4*)(const void*)&x2s[16 * w + quad * 4];
#pragma unroll
      for (int jt = 0; jt < 4; jt++) {
        f32x4 s = f32x4{0.f, 0.f, 0.f, 0.f};
        s = __builtin_amdgcn_mfma_f32_16x16x32_bf16(a0, cf0[jt], s, 0, 0, 0);
        s = __builtin_amdgcn_mfma_f32_16x16x32_bf16(a1, cf1[jt], s, 0, 0, 0);
#pragma unroll
        for (int r = 0; r < 4; r++) {
          float dist = fmaxf(fmaf(-2.0f, s[r], x2p[r] + c2v[jt]), 0.0f);
          Wv[jt][r] = __builtin_amdgcn_rcpf(dist);   // d^(-p/2), p=2
        }
      }
    }

    // ---- rowsum over all 64 j, fully in-register: in-lane over jt, DPP over col.
    //      group16_sum broadcasts within the 16-lane group, which is exactly
    //      the set of lanes sharing this p-quad. Pad mask -> rr = 0. ----
    float rr[4];
#pragma unroll
    for (int r = 0; r < 4; r++) {
      float rs = Wv[0][r] + Wv[1][r] + Wv[2][r] + Wv[3][r];
      rs = group16_sum(rs);
      int pl = 16 * w + quad * 4 + r;
      rr[r] = (pl < np) ? __builtin_amdgcn_rcpf(rs) : 0.0f;
    }

    // ---- um = (W * rr)^2 -> bf16 umT write (hw cvt_pk) ----
#pragma unroll
    for (int jt = 0; jt < 4; jt++) {
      float u0v = Wv[jt][0] * rr[0], u1v = Wv[jt][1] * rr[1];
      float u2v = Wv[jt][2] * rr[2], u3v = Wv[jt][3] * rr[3];
      uint2 pk = {cvtpk_bf16(u0v * u0v, u1v * u1v),
                  cvtpk_bf16(u2v * u2v, u3v * u3v)};
      *(uint2*)(void*)&umT[(16 * jt + col) * LDP + 16 * w + quad * 4] = pk;
    }
    __syncthreads();   // umT is written cross-wave now

    // ---- GEMM2: D2[jt=w][dt] += um^T @ X ;  Dden += um^T @ ones ----
#pragma unroll
    for (int pb = 0; pb < 2; pb++) {
      bf16x8 au = *(const bf16x8*)(const void*)&umT[(16 * w + col) * LDP + pb * 32 + quad * 8];
      Dden = __builtin_amdgcn_mfma_f32_16x16x32_bf16(au, onesf, Dden, 0, 0, 0);
#pragma unroll
      for (int dt = 0; dt < 4; dt++) {
        bf16x8 bx = *(const bf16x8*)(const void*)&XTb[(dt * 16 + col) * LDP + pb * 32 + quad * 8];
        D2[dt] = __builtin_amdgcn_mfma_f32_16x16x32_bf16(au, bx, D2[dt], 0, 0, 0);
      }
    }
  }

  // ---- epilogue: write per-block partial (den from MFMA, col-duplicated) ----
  float* pbuf = partial + (size_t)blockIdx.x * PARTIAL_STRIDE;
  if (col == 0) {
    float4 dv = {Dden[0], Dden[1], Dden[2], Dden[3]};
    *(float4*)(void*)&pbuf[CL * DM + 16 * w + quad * 4] = dv;
  }
#pragma unroll
  for (int dt = 0; dt < 4; dt++)
#pragma unroll
    for (int r = 0; r < 4; r++)
      pbuf[(size_t)(16 * w + quad * 4 + r) * DM + dt * 16 + col] = D2[dt][r];
}

// Sum partials -> C_new; Frobenius diff; last block (ticket) does convergence check.
__global__ __launch_bounds__(1024, 1)
void fcm_reduce(const float* __restrict__ partial, float* __restrict__ Cnew,
                const float* __restrict__ Cold, float* __restrict__ out,
                float* __restrict__ diffac, int* __restrict__ done,
                int* __restrict__ ticket, int compute_diff, int nb) {
  if (compute_diff && *done) return;
  __shared__ float sm[16 * 64];
  __shared__ float sden[1024];
  __shared__ int lastflag;
  __shared__ float sdiff;
  int j = blockIdx.x;
  int tid = threadIdx.x;
  int d = tid & 63;
  int slice = tid >> 6;
  float s = 0.0f;
  for (int b = slice; b < nb; b += 16)
    s += partial[(size_t)b * PARTIAL_STRIDE + j * DM + d];
  sm[slice * 64 + d] = s;
  float dv = 0.0f;
  for (int b = tid; b < nb; b += 1024)
    dv += partial[(size_t)b * PARTIAL_STRIDE + CL * DM + j];
  sden[tid] = dv;
  __syncthreads();
#pragma unroll
  for (int st = 8; st; st >>= 1) {
    if (slice < st) sm[slice * 64 + d] += sm[(slice + st) * 64 + d];
    __syncthreads();
  }
#pragma unroll
  for (int st = 512; st >= 64; st >>= 1) {
    if (tid < st) sden[tid] += sden[tid + st];
    __syncthreads();
  }
  if (tid < 64) {
    float denj = wave_sum(sden[tid]);
    float c = sm[tid] / denj;
    Cnew[j * DM + tid] = c;
    if (compute_diff) {
      float df = c - Cold[j * DM + tid];
      float tot = wave_sum(df * df);
      if (tid == 0) atomicAdd(diffac, tot);
    }
  }
  if (!compute_diff) return;
  __syncthreads();
  if (tid == 0) {
    __threadfence();
    int t = atomicAdd(ticket, 1);
    lastflag = (t == (int)gridDim.x - 1);
  }
  __syncthreads();
  if (!lastflag) return;
  if (tid == 0) sdiff = atomicAdd(diffac, 0.0f);
  __syncthreads();
  if (sdiff < 1e-16f) {                 // diff < 1e-8  <=>  diff^2 < 1e-16
    for (int i = tid; i < CL * DM; i += 1024) out[i] = Cold[i];
    if (tid == 0) *done = 1;
  }
  if (tid == 0) { *diffac = 0.0f; *ticket = 0; }
}

// If never converged, V = C_25.
__global__ void fcm_final(const float* __restrict__ Clast, float* __restrict__ out,
                          const int* __restrict__ done) {
  if (*done) return;
  int i = blockIdx.x * blockDim.x + threadIdx.x;
  if (i < CL * DM) out[i] = Clast[i];
}

extern "C" void kernel_launch(void* const* d_in, const int* in_sizes, int n_in,
                              void* d_out, int out_size, void* d_ws, size_t ws_size,
                              hipStream_t stream) {
  const float* data = (const float*)d_in[0];
  const float* u0   = (const float*)d_in[1];
  float* out = (float*)d_out;
  int N = in_sizes[0] / DM;            // 300000
  int ntiles = (N + 63) / 64;          // 4688

  float* ws = (float*)d_ws;
  size_t Noff = ((size_t)N + 15) & ~(size_t)15;
  float* x2 = ws;                                  // N fp32
  unsigned short* xbf = (unsigned short*)(ws + Noff);  // N*64 bf16 = N*32 float slots
  float* C0 = ws + Noff + (size_t)N * 32;
  float* C1 = C0 + CL * DM;
  float* diffac = C1 + CL * DM;
  int* done = (int*)(diffac + 1);
  int* ticket = (int*)(diffac + 2);
  float* partial = diffac + 16;

  size_t used = Noff + (size_t)N * 32 + 2 * CL * DM + 16;
  size_t avail = (ws_size / 4 > used) ? (ws_size / 4 - used) / PARTIAL_STRIDE : 0;
  int nb = (int)(avail < MAX_BLOCKS ? avail : MAX_BLOCKS);
  if (nb < 1) nb = 1;

  size_t nvec = (size_t)N * (DM / 4);
  hipLaunchKernelGGL(fcm_prep, dim3((unsigned)((nvec + 255) / 256)), dim3(256), 0,
                     stream, data, x2, xbf, diffac, done, ticket, N);
  hipLaunchKernelGGL((fcm_pass<true>), dim3(nb), dim3(256), 0, stream,
                     xbf, x2, u0, partial, done, N, ntiles);
  hipLaunchKernelGGL(fcm_reduce, dim3(64), dim3(1024), 0, stream,
                     partial, C0, C1, out, diffac, done, ticket, 0, nb);

  float* bufs[2] = {C0, C1};
  for (int k = 0; k < MAX_ITER; k++) {
    float* Cc = bufs[k & 1];
    float* Cn = bufs[(k + 1) & 1];
    hipLaunchKernelGGL((fcm_pass<false>), dim3(nb), dim3(256), 0, stream,
                       xbf, x2, Cc, partial, done, N, ntiles);
    hipLaunchKernelGGL(fcm_reduce, dim3(64), dim3(1024), 0, stream,
                       partial, Cn, Cc, out, diffac, done, ticket, 1, nb);
  }
  hipLaunchKernelGGL(fcm_final, dim3(16), dim3(256), 0, stream,
                     bufs[1], out, done);
}